// Round 1
// baseline (489.414 us; speedup 1.0000x reference)
//
#include <hip/hip_runtime.h>

#define ZP (-1.0e10f)

constexpr int TT = 2048;   // time steps
constexpr int BB = 64;     // batch
constexpr int CC = 256;    // classes
constexpr int LL = 128;    // target length
constexpr int PP = 2 * LL + 1;  // 257 trellis states
constexpr int HT = TT / 2;      // 1024, per-direction steps
constexpr int SPL = 5;          // states per lane (5*52 >= 257)
constexpr int PADP = 260;       // padded P for ws rows
constexpr int NDEN = 512;       // denom blocks (64 b * 8 t-chunks)

__device__ __forceinline__ float lse3f(float a, float b, float c) {
  float m = fmaxf(fmaxf(a, b), c);
  float s = __expf(a - m) + __expf(b - m) + __expf(c - m);
  return m + __logf(s);
}
__device__ __forceinline__ float lse2f(float a, float b) {
  float m = fmaxf(a, b);
  return m + __logf(__expf(a - m) + __expf(b - m));
}

__device__ __forceinline__ int path_at(const int* __restrict__ tg, int p) {
  // blank (class 0) at even p, target label at odd p
  return (p & 1) ? tg[p >> 1] : 0;
}

__global__ __launch_bounds__(256) void ctc_main(
    const float* __restrict__ x, const int* __restrict__ tgt,
    float* __restrict__ S, float* __restrict__ wsA, float* __restrict__ wsB) {
  const int bid = blockIdx.x;

  if (bid < 2 * BB) {
    // ---- trellis recursion: one wave per (batch, direction) ----
    if (threadIdx.x >= 64) return;  // no barriers below: safe early-exit
    const int lane = threadIdx.x;
    const int b = bid & (BB - 1);
    const bool bwd = (bid >= BB);
    const int* tg = tgt + b * LL;
    const float* xb = x + (size_t)b * CC * TT;
    const int pbase = lane * SPL;

    bool valid[SPL];
    bool alw[SPL];
    const float* rp[SPL];
    float af[SPL];
    #pragma unroll
    for (int j = 0; j < SPL; ++j) {
      const int p = pbase + j;
      const bool v = (p < PP);
      valid[j] = v;
      int row = 0;
      if (v && (p & 1)) row = tg[p >> 1];
      rp[j] = xb + (size_t)row * TT;
      if (!bwd) {
        af[j] = (p == 0) ? 0.0f : ZP;
        alw[j] = (v && p >= 2) ? (path_at(tg, p) != path_at(tg, p - 2)) : false;
      } else {
        af[j] = (p == PP - 1) ? 0.0f : ZP;
        alw[j] = (v && (p + 2 < PP)) ? (path_at(tg, p) != path_at(tg, p + 2)) : false;
      }
    }

    if (!bwd) {
      // forward: t = 0 .. HT-1
      float4 cur[SPL], nxt[SPL];
      #pragma unroll
      for (int j = 0; j < SPL; ++j) cur[j] = *(const float4*)(rp[j]);
      for (int tb = 0; tb < HT; tb += 4) {
        #pragma unroll
        for (int j = 0; j < SPL; ++j) nxt[j] = *(const float4*)(rp[j] + tb + 4);
        #pragma unroll
        for (int k = 0; k < 4; ++k) {
          float up4 = __shfl_up(af[4], 1);
          float up3 = __shfl_up(af[3], 1);
          if (lane == 0) { up4 = ZP; up3 = ZP; }
          const float pm1[SPL] = {up4, af[0], af[1], af[2], af[3]};
          const float pm2[SPL] = {up3, up4, af[0], af[1], af[2]};
          float na[SPL];
          #pragma unroll
          for (int j = 0; j < SPL; ++j) {
            const float em = (k == 0) ? cur[j].x : (k == 1) ? cur[j].y
                           : (k == 2) ? cur[j].z : cur[j].w;
            na[j] = lse3f(af[j], pm1[j], alw[j] ? pm2[j] : ZP) + em;
          }
          #pragma unroll
          for (int j = 0; j < SPL; ++j) af[j] = valid[j] ? na[j] : ZP;
        }
        #pragma unroll
        for (int j = 0; j < SPL; ++j) cur[j] = nxt[j];
      }
      #pragma unroll
      for (int j = 0; j < SPL; ++j)
        if (valid[j]) wsA[b * PADP + pbase + j] = af[j];
    } else {
      // backward: t = TT-1 .. HT
      float4 cur[SPL], nxt[SPL];
      #pragma unroll
      for (int j = 0; j < SPL; ++j) cur[j] = *(const float4*)(rp[j] + TT - 4);
      for (int tb = TT - 4; tb >= HT; tb -= 4) {
        const int tn = (tb - 4 >= 0) ? tb - 4 : 0;
        #pragma unroll
        for (int j = 0; j < SPL; ++j) nxt[j] = *(const float4*)(rp[j] + tn);
        #pragma unroll
        for (int k = 3; k >= 0; --k) {
          float dn0 = __shfl_down(af[0], 1);
          float dn1 = __shfl_down(af[1], 1);
          const float pp1[SPL] = {af[1], af[2], af[3], af[4], dn0};
          const float pp2[SPL] = {af[2], af[3], af[4], dn0, dn1};
          float na[SPL];
          #pragma unroll
          for (int j = 0; j < SPL; ++j) {
            const float em = (k == 0) ? cur[j].x : (k == 1) ? cur[j].y
                           : (k == 2) ? cur[j].z : cur[j].w;
            na[j] = lse3f(af[j], pp1[j], alw[j] ? pp2[j] : ZP) + em;
          }
          #pragma unroll
          for (int j = 0; j < SPL; ++j) af[j] = valid[j] ? na[j] : ZP;
        }
        #pragma unroll
        for (int j = 0; j < SPL; ++j) cur[j] = nxt[j];
      }
      #pragma unroll
      for (int j = 0; j < SPL; ++j)
        if (valid[j]) wsB[b * PADP + pbase + j] = af[j];
    }
    return;
  }

  // ---- log-softmax denominator sum: S[b] = sum_t lse_c x[b,c,t] ----
  const int d = bid - 2 * BB;        // 0 .. NDEN-1
  const int b = d >> 3;
  const int t = ((d & 7) << 8) + threadIdx.x;
  const float* xp = x + (size_t)b * CC * TT + t;
  float m = -1e30f, s = 0.0f;
  #pragma unroll 4
  for (int c = 0; c < CC; ++c) {
    const float v = xp[(size_t)c * TT];
    const float nm = fmaxf(m, v);
    s = s * __expf(m - nm) + __expf(v - nm);
    m = nm;
  }
  float dl = m + __logf(s);
  #pragma unroll
  for (int off = 1; off < 64; off <<= 1) dl += __shfl_xor(dl, off);
  if ((threadIdx.x & 63) == 0) atomicAdd(&S[b], dl);
}

__global__ __launch_bounds__(64) void ctc_final(
    const int* __restrict__ tgt, const float* __restrict__ S,
    const float* __restrict__ wsA, const float* __restrict__ wsB,
    float* __restrict__ out) {
  const int b = blockIdx.x;
  const int lane = threadIdx.x;
  const int* tg = tgt + b * LL;
  const int pbase = lane * SPL;

  float a[SPL], bt[SPL];
  bool valid[SPL], alw[SPL];
  #pragma unroll
  for (int j = 0; j < SPL; ++j) {
    const int p = pbase + j;
    const bool v = (p < PP);
    valid[j] = v;
    a[j] = v ? wsA[b * PADP + p] : ZP;
    bt[j] = v ? wsB[b * PADP + p] : ZP;
    alw[j] = (v && (p + 2 < PP)) ? (path_at(tg, p) != path_at(tg, p + 2)) : false;
  }
  const float dn0 = __shfl_down(bt[0], 1);
  const float dn1 = __shfl_down(bt[1], 1);
  const float pp1[SPL] = {bt[1], bt[2], bt[3], bt[4], dn0};
  const float pp2[SPL] = {bt[2], bt[3], bt[4], dn0, dn1};
  float v = ZP;
  #pragma unroll
  for (int j = 0; j < SPL; ++j) {
    if (valid[j]) {
      const float comb = a[j] + lse3f(bt[j], pp1[j], alw[j] ? pp2[j] : ZP);
      v = lse2f(v, comb);
    }
  }
  #pragma unroll
  for (int off = 1; off < 64; off <<= 1) v = lse2f(v, __shfl_xor(v, off));
  if (lane == 0) out[b] = S[b] - v;
}

extern "C" void kernel_launch(void* const* d_in, const int* in_sizes, int n_in,
                              void* d_out, int out_size, void* d_ws, size_t ws_size,
                              hipStream_t stream) {
  const float* x = (const float*)d_in[0];
  const int* tgt = (const int*)d_in[1];
  float* out = (float*)d_out;

  float* S = (float*)d_ws;            // 64 floats
  float* wsA = S + 64;                // 64 * PADP
  float* wsB = wsA + BB * PADP;       // 64 * PADP

  hipMemsetAsync(d_ws, 0, 64 * sizeof(float), stream);
  ctc_main<<<dim3(2 * BB + NDEN), dim3(256), 0, stream>>>(x, tgt, S, wsA, wsB);
  ctc_final<<<dim3(BB), dim3(64), 0, stream>>>(tgt, S, wsA, wsB, out);
}